// Round 2
// baseline (1142.899 us; speedup 1.0000x reference)
//
#include <hip/hip_runtime.h>
#include <hip/hip_bf16.h>
#include <stdint.h>

#define MEMN 500000
#define FEAT 256
#define BATCHN 128
#define SAMP 8192
#define SSTRIDE 61
#define CAP 16384
#define LCAP 28
#define NTILES ((MEMN + 63) / 64)

typedef __bf16 bf16x8 __attribute__((ext_vector_type(8)));
typedef float float4v __attribute__((ext_vector_type(4)));

__device__ __forceinline__ float bf2f(unsigned bits) {
    return __uint_as_float(bits << 16);
}

// pack 8 fp32 (two uint4 views) -> 8 bf16 by truncation
__device__ __forceinline__ uint4 pack8(const uint4 u0, const uint4 u1) {
    uint4 p;
    p.x = (u0.y & 0xffff0000u) | (u0.x >> 16);
    p.y = (u0.w & 0xffff0000u) | (u0.z >> 16);
    p.z = (u1.y & 0xffff0000u) | (u1.x >> 16);
    p.w = (u1.w & 0xffff0000u) | (u1.z >> 16);
    return p;
}

// ---------------- K0: xsq per batch row; zero counters ----------------
__global__ void k0_prep(const float* __restrict__ x, float* __restrict__ xsq,
                        unsigned* __restrict__ cnt, float* __restrict__ dpos) {
    int t = threadIdx.x;
    if (t < BATCHN) {
        const float4* row = (const float4*)(x + t * FEAT);
        float s = 0.f;
        for (int i = 0; i < FEAT / 4; i++) {
            float4 v = row[i];
            s += v.x * v.x + v.y * v.y + v.z * v.z + v.w * v.w;
        }
        xsq[t] = s;
        cnt[t] = 0u;
        dpos[t] = 0.f;
    }
}

// ---------------- K1: sampled distances (8 Mem rows / block) ----------------
__global__ void k1_sample(const float* __restrict__ x, const float* __restrict__ Mem,
                          const float* __restrict__ xsq, float* __restrict__ samp) {
    __shared__ ushort mrow[8][FEAT];   // bf16-truncated sample rows
    __shared__ float msq[8];
    int t = threadIdx.x;
    int s0 = blockIdx.x * 8;
    {
        int r = t >> 5, c = (t & 31) * 8;
        long mr = (long)(s0 + r) * SSTRIDE;
        if (mr >= MEMN) mr -= MEMN;        // wrap: keep sample in-bounds
        const uint4* mp = (const uint4*)(Mem + mr * FEAT + c);
        uint4 u0 = mp[0], u1 = mp[1];
        *(uint4*)(&mrow[r][c]) = pack8(u0, u1);
    }
    __syncthreads();
    if (t < 8) {
        float s = 0.f;
        for (int k = 0; k < FEAT; k++) { float a = bf2f(mrow[t][k]); s += a * a; }
        msq[t] = s;
    }
    __syncthreads();
    for (int q = 0; q < 4; q++) {
        int pair = t + q * 256;
        int sl = pair >> 7, b = pair & 127;
        const float4* xr = (const float4*)(x + b * FEAT);
        float dot = 0.f;
        for (int i = 0; i < FEAT / 8; i++) {
            float4 x0 = xr[2 * i], x1 = xr[2 * i + 1];
            uint4 mv = *(const uint4*)(&mrow[sl][i * 8]);
            unsigned mw[4] = {mv.x, mv.y, mv.z, mv.w};
            float xf[8] = {x0.x, x0.y, x0.z, x0.w, x1.x, x1.y, x1.z, x1.w};
            for (int j = 0; j < 4; j++) {
                dot += xf[2 * j]     * bf2f(mw[j] & 0xffffu)
                     + xf[2 * j + 1] * bf2f(mw[j] >> 16);
            }
        }
        float d = xsq[b] + msq[sl] - 2.f * dot;
        samp[b * SAMP + (s0 + sl)] = d;
    }
}

// ---------------- K2: per-row cutoff from sample histogram ----------------
__global__ void k2_cutoff(const float* __restrict__ samp, float* __restrict__ cutoff) {
    __shared__ unsigned hist[2048];
    __shared__ unsigned part[256];
    int t = threadIdx.x, b = blockIdx.x;
    for (int i = t; i < 2048; i += 256) hist[i] = 0;
    __syncthreads();
    for (int i = t; i < SAMP; i += 256) {
        float d = samp[b * SAMP + i];
        int bin = (int)(d * 2.f);
        bin = bin < 0 ? 0 : (bin > 2047 ? 2047 : bin);
        atomicAdd(&hist[bin], 1u);
    }
    __syncthreads();
    unsigned p = 0;
    for (int j = 0; j < 8; j++) p += hist[t * 8 + j];
    part[t] = p;
    __syncthreads();
    if (t == 0) {
        const unsigned tgt = 98;  // ~1.2% of 8192 -> ~6000 candidates of 500000
        unsigned cum = 0; int binsel = 2047;
        for (int i = 0; i < 256; i++) {
            if (cum + part[i] >= tgt) {
                for (int j = 0; j < 8; j++) {
                    int bb = i * 8 + j;
                    cum += hist[bb];
                    if (cum >= tgt) { binsel = bb; break; }
                }
                break;
            }
            cum += part[i];
        }
        cutoff[b] = (binsel + 1) * 0.5f + 1.0f;
    }
}

// ---------------- K3: main MFMA GEMM + filtered append ----------------
// v3: cross-tile register double-buffering. Issue tile i+1's 16 dwordx4 Mem
//     loads BEFORE computing tile i, so HBM latency hides under MFMA+epilogue
//     (compiler emits counted vmcnt(16), not a per-tile vmcnt(0) drain).
//     VGPR: 128 staging + 32 acc + misc ~= 200, still 2 waves/SIMD.
__launch_bounds__(256, 2)
__global__ void k3_gemm(const float* __restrict__ x, const float* __restrict__ Mem,
                        const int* __restrict__ labels,
                        const float* __restrict__ xsq, const float* __restrict__ cutoff,
                        unsigned* __restrict__ cnt, float* __restrict__ buf,
                        float* __restrict__ dpos) {
    __shared__ ushort xs[BATCHN * FEAT];        // 64 KiB, 16B-chunk XOR swizzle
    __shared__ float cbuf[BATCHN * LCAP];       // 14 KiB candidate staging
    __shared__ unsigned ccnt[BATCHN];           // 512 B
    int t = threadIdx.x;
    if (t < BATCHN) ccnt[t] = 0u;
    // stage whole x (128x256) into LDS as bf16; chunk' = chunk ^ (row&7)
    for (int i = 0; i < 16; i++) {
        int c = i * 256 + t;               // 8-float chunk id, < 4096
        int row = c >> 5, cc = c & 31;
        int ccs = cc ^ (row & 7);
        const uint4* xp = (const uint4*)(x + row * FEAT + cc * 8);
        uint4 u0 = xp[0], u1 = xp[1];
        *(uint4*)(&xs[row * FEAT + ccs * 8]) = pack8(u0, u1);
    }
    int lane = t & 63, wave = t >> 6;
    int l15 = lane & 15, quad = lane >> 4;
    int rx = l15 & 7;                       // read-side swizzle key (row&7)
    float xsq_v[8], cut_v[8];
    int lab_v[8];
    for (int nt = 0; nt < 8; nt++) {
        int b = nt * 16 + l15;
        xsq_v[nt] = xsq[b];
        cut_v[nt] = cutoff[b];
        lab_v[nt] = labels[b];
    }
    __syncthreads();

    // ---- issue all 16 global loads for one tile into a register set ----
    auto load_tile = [&](uint4* ua, uint4* ub, int tile) {
        int mbase = tile * 64 + wave * 16;
        int m0 = mbase + l15;
        long mA = m0 < MEMN ? m0 : (MEMN - 1);
        const float* aptr = Mem + mA * FEAT + quad * 8;
#pragma unroll
        for (int ks = 0; ks < 8; ks++) {
            const uint4* ap = (const uint4*)(aptr + ks * 32);
            ua[ks] = ap[0];
            ub[ks] = ap[1];
        }
    };

    // ---- MFMA + distance epilogue for one staged tile ----
    auto compute_tile = [&](const uint4* ua, const uint4* ub, int tile) {
        int mbase = tile * 64 + wave * 16;
        float4v acc[8];
#pragma unroll
        for (int nt = 0; nt < 8; nt++) acc[nt] = (float4v){0.f, 0.f, 0.f, 0.f};
        float msqp = 0.f;
#pragma unroll
        for (int ks = 0; ks < 8; ks++) {
            float4 f0 = __builtin_bit_cast(float4, ua[ks]);
            float4 f1 = __builtin_bit_cast(float4, ub[ks]);
            msqp += f0.x * f0.x + f0.y * f0.y + f0.z * f0.z + f0.w * f0.w
                  + f1.x * f1.x + f1.y * f1.y + f1.z * f1.z + f1.w * f1.w;
            uint4 av = pack8(ua[ks], ub[ks]);
            bf16x8 af = __builtin_bit_cast(bf16x8, av);
            int ch = ks * 4 + quad;
#pragma unroll
            for (int nt = 0; nt < 8; nt++) {
                uint4 bv = *(const uint4*)(&xs[(nt * 16 + l15) * FEAT + (ch ^ rx) * 8]);
                bf16x8 bfr = __builtin_bit_cast(bf16x8, bv);
                acc[nt] = __builtin_amdgcn_mfma_f32_16x16x32_bf16(af, bfr, acc[nt], 0, 0, 0);
            }
        }
        // reduce msq across the 4 quads: every lane then holds msq[m = mbase + l15]
        float msqf = msqp;
        msqf += __shfl_xor(msqf, 16, 64);
        msqf += __shfl_xor(msqf, 32, 64);
#pragma unroll
        for (int r = 0; r < 4; r++) {
            float msq_r = __shfl(msqf, quad * 4 + r, 64);  // msq of D-row quad*4+r
            int mg = mbase + quad * 4 + r;
            if (mg < MEMN) {
#pragma unroll
                for (int nt = 0; nt < 8; nt++) {
                    float d = xsq_v[nt] + msq_r - 2.f * acc[nt][r];
                    int b = nt * 16 + l15;
                    if (lab_v[nt] == mg) {
                        dpos[b] = d;
                    } else if (d < cut_v[nt]) {
                        unsigned p = atomicAdd(&ccnt[b], 1u);   // LDS atomic: cheap
                        if (p < LCAP) {
                            cbuf[b * LCAP + p] = d;
                        } else {                                // rare overflow path
                            unsigned q = atomicAdd(&cnt[b], 1u);
                            if (q < CAP) buf[(long)b * CAP + q] = d;
                        }
                    }
                }
            }
        }
    };

    // ---- software-pipelined grid-stride loop (register ping-pong) ----
    uint4 uaA[8], ubA[8], uaB[8], ubB[8];
    const int G = gridDim.x;
    int cur = blockIdx.x;
    if (cur < NTILES) {
        load_tile(uaA, ubA, cur);
        int nxt = cur + G;
        bool useA = true;
        while (cur < NTILES) {
            if (useA) {
                if (nxt < NTILES) load_tile(uaB, ubB, nxt);
                compute_tile(uaA, ubA, cur);
            } else {
                if (nxt < NTILES) load_tile(uaA, ubA, nxt);
                compute_tile(uaB, ubB, cur);
            }
            useA = !useA;
            cur = nxt;
            nxt = cur + G;
        }
    }

    // ---- block-end flush: one global atomic per (block, b) ----
    __syncthreads();
    if (t < BATCHN) {
        unsigned nb = ccnt[t];
        if (nb > LCAP) nb = LCAP;
        if (nb) {
            unsigned p = atomicAdd(&cnt[t], nb);
            for (unsigned i = 0; i < nb; i++) {
                unsigned q = p + i;
                if (q < CAP) buf[(long)t * CAP + q] = cbuf[t * LCAP + i];
            }
        }
    }
}

// ---------------- K4: exact per-row selection of k-1 smallest ----------------
__global__ void k4_select(const float* __restrict__ buf, const unsigned* __restrict__ cnt,
                          const float* __restrict__ cutoff, const float* __restrict__ dpos,
                          const int* __restrict__ topk, float* __restrict__ tri) {
    __shared__ unsigned hist[2048];
    __shared__ unsigned part[256];
    __shared__ float coll[1024];
    __shared__ unsigned ncoll;
    __shared__ int sTb;
    __shared__ unsigned sC1;
    __shared__ float wsum[4];
    int t = threadIdx.x, b = blockIdx.x;
    int k1 = topk[0] - 1;
    unsigned c = cnt[b]; if (c > CAP) c = CAP;
    float invw = 2048.f / cutoff[b];
    for (int i = t; i < 2048; i += 256) hist[i] = 0;
    if (t == 0) ncoll = 0;
    __syncthreads();
    const float* vals = buf + (long)b * CAP;
    for (unsigned i = t; i < c; i += 256) {
        float d = vals[i];
        int bin = (int)(d * invw);
        bin = bin < 0 ? 0 : (bin > 2047 ? 2047 : bin);
        atomicAdd(&hist[bin], 1u);
    }
    __syncthreads();
    unsigned p = 0;
    for (int j = 0; j < 8; j++) p += hist[t * 8 + j];
    part[t] = p;
    __syncthreads();
    if (t == 0) {
        unsigned tgt = (c < (unsigned)k1) ? c : (unsigned)k1;
        unsigned cum = 0; int Tb = 2048; unsigned C1 = 0;
        if (tgt > 0) {
            for (int i = 0; i < 256; i++) {
                if (cum + part[i] >= tgt) {
                    for (int j = 0; j < 8; j++) {
                        int bb = i * 8 + j;
                        if (cum + hist[bb] >= tgt) { Tb = bb; C1 = cum; break; }
                        cum += hist[bb];
                    }
                    break;
                }
                cum += part[i];
            }
        }
        sTb = Tb; sC1 = C1;
    }
    __syncthreads();
    int Tb = sTb; unsigned C1 = sC1;
    float ls = 0.f;
    for (unsigned i = t; i < c; i += 256) {
        float d = vals[i];
        int bin = (int)(d * invw);
        bin = bin < 0 ? 0 : (bin > 2047 ? 2047 : bin);
        if (bin < Tb) ls += d;
        else if (bin == Tb) {
            unsigned ix = atomicAdd(&ncoll, 1u);
            if (ix < 1024) coll[ix] = d;
        }
    }
    ls += __shfl_down(ls, 32, 64); ls += __shfl_down(ls, 16, 64);
    ls += __shfl_down(ls, 8, 64);  ls += __shfl_down(ls, 4, 64);
    ls += __shfl_down(ls, 2, 64);  ls += __shfl_down(ls, 1, 64);
    if ((t & 63) == 0) wsum[t >> 6] = ls;
    __syncthreads();
    if (t == 0) {
        float S = wsum[0] + wsum[1] + wsum[2] + wsum[3];
        unsigned tgt = (c < (unsigned)k1) ? c : (unsigned)k1;
        int r = (int)(tgt - C1);
        unsigned nc = ncoll; if (nc > 1024) nc = 1024;
        for (int i = 0; i < r && i < (int)nc; i++) {
            float mn = 3.4e38f; int mi = 0;
            for (unsigned j = 0; j < nc; j++) if (coll[j] < mn) { mn = coll[j]; mi = (int)j; }
            S += mn; coll[mi] = 3.4e38f;
        }
        float minl = dpos[b];
        minl = minl < 1e-12f ? 1e-12f : (minl > 1e12f ? 1e12f : minl);
        minl += (float)(MEMN - 1) * 1e-12f;  // clip() lifts the M-1 zeros to 1e-12
        float maxl = S / (float)k1;
        float loss = minl - maxl + 1.0f; if (loss < 0.f) loss = 0.f;
        tri[b * 3 + 0] = loss; tri[b * 3 + 1] = minl; tri[b * 3 + 2] = maxl;
    }
}

// ---------------- K5: means -> 3 fp32 outputs ----------------
__global__ void k5_final(const float* __restrict__ tri, float* __restrict__ out) {
    __shared__ float ws2[6];
    int t = threadIdx.x;  // 128 threads
    float l = tri[t * 3 + 0], mi = tri[t * 3 + 1], mx = tri[t * 3 + 2];
    for (int s = 32; s >= 1; s >>= 1) {
        l += __shfl_down(l, s, 64);
        mi += __shfl_down(mi, s, 64);
        mx += __shfl_down(mx, s, 64);
    }
    if ((t & 63) == 0) { int wv = t >> 6; ws2[wv * 3 + 0] = l; ws2[wv * 3 + 1] = mi; ws2[wv * 3 + 2] = mx; }
    __syncthreads();
    if (t == 0) {
        out[0] = (ws2[0] + ws2[3]) * (1.f / 128.f);
        out[1] = (ws2[1] + ws2[4]) * (1.f / 128.f);
        out[2] = (ws2[2] + ws2[5]) * (1.f / 128.f);
    }
}

__global__ void k_sentinel(float* out) {
    out[0] = -777.f; out[1] = -777.f; out[2] = -777.f;
}

extern "C" void kernel_launch(void* const* d_in, const int* in_sizes, int n_in,
                              void* d_out, int out_size, void* d_ws, size_t ws_size,
                              hipStream_t stream) {
    const float* x     = (const float*)d_in[0];
    const int* labels  = (const int*)d_in[1];
    const float* Mem   = (const float*)d_in[2];
    const int* topk    = (const int*)d_in[3];
    (void)in_sizes; (void)n_in; (void)out_size;

    char* ws = (char*)d_ws;
    const size_t OFF_SAMP = 0;                       // 128*8192*4 = 4 MiB
    const size_t OFF_BUF  = 4194304;                 // 128*16384*4 = 8 MiB
    const size_t OFF_CNT  = OFF_BUF + 8388608;
    const size_t OFF_XSQ  = OFF_CNT + 512;
    const size_t OFF_DPOS = OFF_XSQ + 512;
    const size_t OFF_CUT  = OFF_DPOS + 512;
    const size_t OFF_TRI  = OFF_CUT + 512;
    const size_t NEEDED   = OFF_TRI + 1536;
    if (ws_size < NEEDED) {
        k_sentinel<<<1, 1, 0, stream>>>((float*)d_out);
        return;
    }
    float*    samp   = (float*)(ws + OFF_SAMP);
    float*    buf    = (float*)(ws + OFF_BUF);
    unsigned* cnt    = (unsigned*)(ws + OFF_CNT);
    float*    xsq    = (float*)(ws + OFF_XSQ);
    float*    dpos   = (float*)(ws + OFF_DPOS);
    float*    cutoff = (float*)(ws + OFF_CUT);
    float*    tri    = (float*)(ws + OFF_TRI);

    k0_prep  <<<1,    128, 0, stream>>>(x, xsq, cnt, dpos);
    k1_sample<<<1024, 256, 0, stream>>>(x, Mem, xsq, samp);
    k2_cutoff<<<128,  256, 0, stream>>>(samp, cutoff);
    k3_gemm  <<<2048, 256, 0, stream>>>(x, Mem, labels, xsq, cutoff, cnt, buf, dpos);
    k4_select<<<128,  256, 0, stream>>>(buf, cnt, cutoff, dpos, topk, tri);
    k5_final <<<1,    128, 0, stream>>>(tri, (float*)d_out);
}

// Round 3
// 1011.235 us; speedup vs baseline: 1.1302x; 1.1302x over previous
//
#include <hip/hip_runtime.h>
#include <hip/hip_bf16.h>
#include <stdint.h>

#define MEMN 500000
#define FEAT 256
#define BATCHN 128
#define SAMP 8192
#define SSTRIDE 61
#define CAP 16384
#define LCAP 28
#define NTILES ((MEMN + 63) / 64)
#define K3GRID 1024

typedef __bf16 bf16x8 __attribute__((ext_vector_type(8)));
typedef float float4v __attribute__((ext_vector_type(4)));

__device__ __forceinline__ float bf2f(unsigned bits) {
    return __uint_as_float(bits << 16);
}

// pack 8 fp32 (two uint4 views) -> 8 bf16 by truncation
__device__ __forceinline__ uint4 pack8(const uint4 u0, const uint4 u1) {
    uint4 p;
    p.x = (u0.y & 0xffff0000u) | (u0.x >> 16);
    p.y = (u0.w & 0xffff0000u) | (u0.z >> 16);
    p.z = (u1.y & 0xffff0000u) | (u1.x >> 16);
    p.w = (u1.w & 0xffff0000u) | (u1.z >> 16);
    return p;
}

// ---------------- K0: xsq per batch row; zero counters ----------------
__global__ void k0_prep(const float* __restrict__ x, float* __restrict__ xsq,
                        unsigned* __restrict__ cnt, float* __restrict__ dpos) {
    int t = threadIdx.x;
    if (t < BATCHN) {
        const float4* row = (const float4*)(x + t * FEAT);
        float s = 0.f;
        for (int i = 0; i < FEAT / 4; i++) {
            float4 v = row[i];
            s += v.x * v.x + v.y * v.y + v.z * v.z + v.w * v.w;
        }
        xsq[t] = s;
        cnt[t] = 0u;
        dpos[t] = 0.f;
    }
}

// ---------------- K1: sampled distances (8 Mem rows / block) ----------------
__global__ void k1_sample(const float* __restrict__ x, const float* __restrict__ Mem,
                          const float* __restrict__ xsq, float* __restrict__ samp) {
    __shared__ ushort mrow[8][FEAT];   // bf16-truncated sample rows
    __shared__ float msq[8];
    int t = threadIdx.x;
    int s0 = blockIdx.x * 8;
    {
        int r = t >> 5, c = (t & 31) * 8;
        long mr = (long)(s0 + r) * SSTRIDE;
        if (mr >= MEMN) mr -= MEMN;        // wrap: keep sample in-bounds
        const uint4* mp = (const uint4*)(Mem + mr * FEAT + c);
        uint4 u0 = mp[0], u1 = mp[1];
        *(uint4*)(&mrow[r][c]) = pack8(u0, u1);
    }
    __syncthreads();
    if (t < 8) {
        float s = 0.f;
        for (int k = 0; k < FEAT; k++) { float a = bf2f(mrow[t][k]); s += a * a; }
        msq[t] = s;
    }
    __syncthreads();
    for (int q = 0; q < 4; q++) {
        int pair = t + q * 256;
        int sl = pair >> 7, b = pair & 127;
        const float4* xr = (const float4*)(x + b * FEAT);
        float dot = 0.f;
        for (int i = 0; i < FEAT / 8; i++) {
            float4 x0 = xr[2 * i], x1 = xr[2 * i + 1];
            uint4 mv = *(const uint4*)(&mrow[sl][i * 8]);
            unsigned mw[4] = {mv.x, mv.y, mv.z, mv.w};
            float xf[8] = {x0.x, x0.y, x0.z, x0.w, x1.x, x1.y, x1.z, x1.w};
            for (int j = 0; j < 4; j++) {
                dot += xf[2 * j]     * bf2f(mw[j] & 0xffffu)
                     + xf[2 * j + 1] * bf2f(mw[j] >> 16);
            }
        }
        float d = xsq[b] + msq[sl] - 2.f * dot;
        samp[b * SAMP + (s0 + sl)] = d;
    }
}

// ---------------- K2: per-row cutoff from sample histogram ----------------
__global__ void k2_cutoff(const float* __restrict__ samp, float* __restrict__ cutoff) {
    __shared__ unsigned hist[2048];
    __shared__ unsigned part[256];
    int t = threadIdx.x, b = blockIdx.x;
    for (int i = t; i < 2048; i += 256) hist[i] = 0;
    __syncthreads();
    for (int i = t; i < SAMP; i += 256) {
        float d = samp[b * SAMP + i];
        int bin = (int)(d * 2.f);
        bin = bin < 0 ? 0 : (bin > 2047 ? 2047 : bin);
        atomicAdd(&hist[bin], 1u);
    }
    __syncthreads();
    unsigned p = 0;
    for (int j = 0; j < 8; j++) p += hist[t * 8 + j];
    part[t] = p;
    __syncthreads();
    if (t == 0) {
        const unsigned tgt = 98;  // ~1.2% of 8192 -> ~6000 candidates of 500000
        unsigned cum = 0; int binsel = 2047;
        for (int i = 0; i < 256; i++) {
            if (cum + part[i] >= tgt) {
                for (int j = 0; j < 8; j++) {
                    int bb = i * 8 + j;
                    cum += hist[bb];
                    if (cum >= tgt) { binsel = bb; break; }
                }
                break;
            }
            cum += part[i];
        }
        cutoff[b] = (binsel + 1) * 0.5f + 1.0f;
    }
}

// ---------------- K3: main MFMA GEMM + filtered append ----------------
// v4: cross-tile register double-buffer done with MACROS (no lambdas, no
//     pointer-passed arrays -> no address escape -> no scratch spills, cf.
//     v3's WRITE_SIZE=600MB at VGPR=128). Pipeline unrolled x2 so buffer
//     choice is static (no runtime ping-pong flag). All staging-array
//     indices are literals inside #pragma unroll loops.
#define K3_LOAD(P, tileexpr) do {                                              \
    int mbase_ = (tileexpr) * 64 + wave * 16;                                  \
    int m0_ = mbase_ + l15;                                                    \
    long mA_ = m0_ < MEMN ? m0_ : (MEMN - 1);                                  \
    const uint4* ap_ = (const uint4*)(Mem + mA_ * FEAT + quad * 8);            \
    _Pragma("unroll")                                                          \
    for (int ks = 0; ks < 8; ks++) {                                           \
        P[2 * ks]     = ap_[ks * 8];                                           \
        P[2 * ks + 1] = ap_[ks * 8 + 1];                                       \
    }                                                                          \
} while (0)

#define K3_COMPUTE(P, tileexpr) do {                                           \
    int mbase_ = (tileexpr) * 64 + wave * 16;                                  \
    float4v acc_[8];                                                           \
    _Pragma("unroll")                                                          \
    for (int nt = 0; nt < 8; nt++) acc_[nt] = (float4v){0.f, 0.f, 0.f, 0.f};   \
    float msqp_ = 0.f;                                                         \
    _Pragma("unroll")                                                          \
    for (int ks = 0; ks < 8; ks++) {                                           \
        float4 f0_ = __builtin_bit_cast(float4, P[2 * ks]);                    \
        float4 f1_ = __builtin_bit_cast(float4, P[2 * ks + 1]);                \
        msqp_ += f0_.x * f0_.x + f0_.y * f0_.y + f0_.z * f0_.z + f0_.w * f0_.w \
               + f1_.x * f1_.x + f1_.y * f1_.y + f1_.z * f1_.z + f1_.w * f1_.w;\
        uint4 av_ = pack8(P[2 * ks], P[2 * ks + 1]);                           \
        bf16x8 af_ = __builtin_bit_cast(bf16x8, av_);                          \
        int ch_ = ks * 4 + quad;                                               \
        _Pragma("unroll")                                                      \
        for (int nt = 0; nt < 8; nt++) {                                       \
            uint4 bv_ = *(const uint4*)(&xs[(nt * 16 + l15) * FEAT             \
                                            + (ch_ ^ rx) * 8]);               \
            bf16x8 bf_ = __builtin_bit_cast(bf16x8, bv_);                      \
            acc_[nt] = __builtin_amdgcn_mfma_f32_16x16x32_bf16(af_, bf_,       \
                                                               acc_[nt],       \
                                                               0, 0, 0);       \
        }                                                                      \
    }                                                                          \
    float msqf_ = msqp_;                                                       \
    msqf_ += __shfl_xor(msqf_, 16, 64);                                        \
    msqf_ += __shfl_xor(msqf_, 32, 64);                                        \
    _Pragma("unroll")                                                          \
    for (int r = 0; r < 4; r++) {                                              \
        float msq_r_ = __shfl(msqf_, quad * 4 + r, 64);                        \
        int mg_ = mbase_ + quad * 4 + r;                                       \
        if (mg_ < MEMN) {                                                      \
            _Pragma("unroll")                                                  \
            for (int nt = 0; nt < 8; nt++) {                                   \
                float d_ = xsq_v[nt] + msq_r_ - 2.f * acc_[nt][r];             \
                int b_ = nt * 16 + l15;                                        \
                if (lab_v[nt] == mg_) {                                        \
                    dpos[b_] = d_;                                             \
                } else if (d_ < cut_v[nt]) {                                   \
                    unsigned p_ = atomicAdd(&ccnt[b_], 1u);                    \
                    if (p_ < LCAP) {                                           \
                        cbuf[b_ * LCAP + p_] = d_;                             \
                    } else {                                                   \
                        unsigned q_ = atomicAdd(&cnt[b_], 1u);                 \
                        if (q_ < CAP) buf[(long)b_ * CAP + q_] = d_;           \
                    }                                                          \
                }                                                              \
            }                                                                  \
        }                                                                      \
    }                                                                          \
} while (0)

__launch_bounds__(256, 2)
__global__ void k3_gemm(const float* __restrict__ x, const float* __restrict__ Mem,
                        const int* __restrict__ labels,
                        const float* __restrict__ xsq, const float* __restrict__ cutoff,
                        unsigned* __restrict__ cnt, float* __restrict__ buf,
                        float* __restrict__ dpos) {
    __shared__ ushort xs[BATCHN * FEAT];        // 64 KiB, 16B-chunk XOR swizzle
    __shared__ float cbuf[BATCHN * LCAP];       // 14 KiB candidate staging
    __shared__ unsigned ccnt[BATCHN];           // 512 B
    int t = threadIdx.x;
    if (t < BATCHN) ccnt[t] = 0u;
    // stage whole x (128x256) into LDS as bf16; chunk' = chunk ^ (row&7)
    for (int i = 0; i < 16; i++) {
        int c = i * 256 + t;               // 8-float chunk id, < 4096
        int row = c >> 5, cc = c & 31;
        int ccs = cc ^ (row & 7);
        const uint4* xp = (const uint4*)(x + row * FEAT + cc * 8);
        uint4 u0 = xp[0], u1 = xp[1];
        *(uint4*)(&xs[row * FEAT + ccs * 8]) = pack8(u0, u1);
    }
    int lane = t & 63, wave = t >> 6;
    int l15 = lane & 15, quad = lane >> 4;
    int rx = l15 & 7;                       // read-side swizzle key (row&7)
    float xsq_v[8], cut_v[8];
    int lab_v[8];
#pragma unroll
    for (int nt = 0; nt < 8; nt++) {
        int b = nt * 16 + l15;
        xsq_v[nt] = xsq[b];
        cut_v[nt] = cutoff[b];
        lab_v[nt] = labels[b];
    }
    __syncthreads();

    // ---- software-pipelined grid-stride loop, unrolled x2 (static buffers) --
    uint4 bufA[16], bufB[16];
    const int G = K3GRID;
    int t0 = blockIdx.x;
    if (t0 < NTILES) {
        K3_LOAD(bufA, t0);
        for (int tile = t0; tile < NTILES; tile += 2 * G) {
            int tn1 = tile + G;
            if (tn1 < NTILES) K3_LOAD(bufB, tn1);
            K3_COMPUTE(bufA, tile);
            int tn2 = tile + 2 * G;
            if (tn2 < NTILES) K3_LOAD(bufA, tn2);
            if (tn1 < NTILES) K3_COMPUTE(bufB, tn1);
        }
    }

    // ---- block-end flush: one global atomic per (block, b) ----
    __syncthreads();
    if (t < BATCHN) {
        unsigned nb = ccnt[t];
        if (nb > LCAP) nb = LCAP;
        if (nb) {
            unsigned p = atomicAdd(&cnt[t], nb);
            for (unsigned i = 0; i < nb; i++) {
                unsigned q = p + i;
                if (q < CAP) buf[(long)t * CAP + q] = cbuf[t * LCAP + i];
            }
        }
    }
}

// ---------------- K4: exact per-row selection of k-1 smallest ----------------
__global__ void k4_select(const float* __restrict__ buf, const unsigned* __restrict__ cnt,
                          const float* __restrict__ cutoff, const float* __restrict__ dpos,
                          const int* __restrict__ topk, float* __restrict__ tri) {
    __shared__ unsigned hist[2048];
    __shared__ unsigned part[256];
    __shared__ float coll[1024];
    __shared__ unsigned ncoll;
    __shared__ int sTb;
    __shared__ unsigned sC1;
    __shared__ float wsum[4];
    int t = threadIdx.x, b = blockIdx.x;
    int k1 = topk[0] - 1;
    unsigned c = cnt[b]; if (c > CAP) c = CAP;
    float invw = 2048.f / cutoff[b];
    for (int i = t; i < 2048; i += 256) hist[i] = 0;
    if (t == 0) ncoll = 0;
    __syncthreads();
    const float* vals = buf + (long)b * CAP;
    for (unsigned i = t; i < c; i += 256) {
        float d = vals[i];
        int bin = (int)(d * invw);
        bin = bin < 0 ? 0 : (bin > 2047 ? 2047 : bin);
        atomicAdd(&hist[bin], 1u);
    }
    __syncthreads();
    unsigned p = 0;
    for (int j = 0; j < 8; j++) p += hist[t * 8 + j];
    part[t] = p;
    __syncthreads();
    if (t == 0) {
        unsigned tgt = (c < (unsigned)k1) ? c : (unsigned)k1;
        unsigned cum = 0; int Tb = 2048; unsigned C1 = 0;
        if (tgt > 0) {
            for (int i = 0; i < 256; i++) {
                if (cum + part[i] >= tgt) {
                    for (int j = 0; j < 8; j++) {
                        int bb = i * 8 + j;
                        if (cum + hist[bb] >= tgt) { Tb = bb; C1 = cum; break; }
                        cum += hist[bb];
                    }
                    break;
                }
                cum += part[i];
            }
        }
        sTb = Tb; sC1 = C1;
    }
    __syncthreads();
    int Tb = sTb; unsigned C1 = sC1;
    float ls = 0.f;
    for (unsigned i = t; i < c; i += 256) {
        float d = vals[i];
        int bin = (int)(d * invw);
        bin = bin < 0 ? 0 : (bin > 2047 ? 2047 : bin);
        if (bin < Tb) ls += d;
        else if (bin == Tb) {
            unsigned ix = atomicAdd(&ncoll, 1u);
            if (ix < 1024) coll[ix] = d;
        }
    }
    ls += __shfl_down(ls, 32, 64); ls += __shfl_down(ls, 16, 64);
    ls += __shfl_down(ls, 8, 64);  ls += __shfl_down(ls, 4, 64);
    ls += __shfl_down(ls, 2, 64);  ls += __shfl_down(ls, 1, 64);
    if ((t & 63) == 0) wsum[t >> 6] = ls;
    __syncthreads();
    if (t == 0) {
        float S = wsum[0] + wsum[1] + wsum[2] + wsum[3];
        unsigned tgt = (c < (unsigned)k1) ? c : (unsigned)k1;
        int r = (int)(tgt - C1);
        unsigned nc = ncoll; if (nc > 1024) nc = 1024;
        for (int i = 0; i < r && i < (int)nc; i++) {
            float mn = 3.4e38f; int mi = 0;
            for (unsigned j = 0; j < nc; j++) if (coll[j] < mn) { mn = coll[j]; mi = (int)j; }
            S += mn; coll[mi] = 3.4e38f;
        }
        float minl = dpos[b];
        minl = minl < 1e-12f ? 1e-12f : (minl > 1e12f ? 1e12f : minl);
        minl += (float)(MEMN - 1) * 1e-12f;  // clip() lifts the M-1 zeros to 1e-12
        float maxl = S / (float)k1;
        float loss = minl - maxl + 1.0f; if (loss < 0.f) loss = 0.f;
        tri[b * 3 + 0] = loss; tri[b * 3 + 1] = minl; tri[b * 3 + 2] = maxl;
    }
}

// ---------------- K5: means -> 3 fp32 outputs ----------------
__global__ void k5_final(const float* __restrict__ tri, float* __restrict__ out) {
    __shared__ float ws2[6];
    int t = threadIdx.x;  // 128 threads
    float l = tri[t * 3 + 0], mi = tri[t * 3 + 1], mx = tri[t * 3 + 2];
    for (int s = 32; s >= 1; s >>= 1) {
        l += __shfl_down(l, s, 64);
        mi += __shfl_down(mi, s, 64);
        mx += __shfl_down(mx, s, 64);
    }
    if ((t & 63) == 0) { int wv = t >> 6; ws2[wv * 3 + 0] = l; ws2[wv * 3 + 1] = mi; ws2[wv * 3 + 2] = mx; }
    __syncthreads();
    if (t == 0) {
        out[0] = (ws2[0] + ws2[3]) * (1.f / 128.f);
        out[1] = (ws2[1] + ws2[4]) * (1.f / 128.f);
        out[2] = (ws2[2] + ws2[5]) * (1.f / 128.f);
    }
}

__global__ void k_sentinel(float* out) {
    out[0] = -777.f; out[1] = -777.f; out[2] = -777.f;
}

extern "C" void kernel_launch(void* const* d_in, const int* in_sizes, int n_in,
                              void* d_out, int out_size, void* d_ws, size_t ws_size,
                              hipStream_t stream) {
    const float* x     = (const float*)d_in[0];
    const int* labels  = (const int*)d_in[1];
    const float* Mem   = (const float*)d_in[2];
    const int* topk    = (const int*)d_in[3];
    (void)in_sizes; (void)n_in; (void)out_size;

    char* ws = (char*)d_ws;
    const size_t OFF_SAMP = 0;                       // 128*8192*4 = 4 MiB
    const size_t OFF_BUF  = 4194304;                 // 128*16384*4 = 8 MiB
    const size_t OFF_CNT  = OFF_BUF + 8388608;
    const size_t OFF_XSQ  = OFF_CNT + 512;
    const size_t OFF_DPOS = OFF_XSQ + 512;
    const size_t OFF_CUT  = OFF_DPOS + 512;
    const size_t OFF_TRI  = OFF_CUT + 512;
    const size_t NEEDED   = OFF_TRI + 1536;
    if (ws_size < NEEDED) {
        k_sentinel<<<1, 1, 0, stream>>>((float*)d_out);
        return;
    }
    float*    samp   = (float*)(ws + OFF_SAMP);
    float*    buf    = (float*)(ws + OFF_BUF);
    unsigned* cnt    = (unsigned*)(ws + OFF_CNT);
    float*    xsq    = (float*)(ws + OFF_XSQ);
    float*    dpos   = (float*)(ws + OFF_DPOS);
    float*    cutoff = (float*)(ws + OFF_CUT);
    float*    tri    = (float*)(ws + OFF_TRI);

    k0_prep  <<<1,      128, 0, stream>>>(x, xsq, cnt, dpos);
    k1_sample<<<1024,   256, 0, stream>>>(x, Mem, xsq, samp);
    k2_cutoff<<<128,    256, 0, stream>>>(samp, cutoff);
    k3_gemm  <<<K3GRID, 256, 0, stream>>>(x, Mem, labels, xsq, cutoff, cnt, buf, dpos);
    k4_select<<<128,    256, 0, stream>>>(buf, cnt, cutoff, dpos, topk, tri);
    k5_final <<<1,      128, 0, stream>>>(tri, (float*)d_out);
}

// Round 4
// 884.635 us; speedup vs baseline: 1.2919x; 1.1431x over previous
//
#include <hip/hip_runtime.h>
#include <hip/hip_bf16.h>
#include <stdint.h>

#define MEMN 500000
#define FEAT 256
#define BATCHN 128
#define SAMP 8192
#define SSTRIDE 61
#define CAP 16384
#define LCAP 28
#define TILE_ROWS 128
#define NTILES ((MEMN + TILE_ROWS - 1) / TILE_ROWS)
#define K3GRID 1024

typedef __bf16 bf16x8 __attribute__((ext_vector_type(8)));
typedef float float4v __attribute__((ext_vector_type(4)));

__device__ __forceinline__ float bf2f(unsigned bits) {
    return __uint_as_float(bits << 16);
}

// pack 8 fp32 (two uint4 views) -> 8 bf16 by truncation
__device__ __forceinline__ uint4 pack8(const uint4 u0, const uint4 u1) {
    uint4 p;
    p.x = (u0.y & 0xffff0000u) | (u0.x >> 16);
    p.y = (u0.w & 0xffff0000u) | (u0.z >> 16);
    p.z = (u1.y & 0xffff0000u) | (u1.x >> 16);
    p.w = (u1.w & 0xffff0000u) | (u1.z >> 16);
    return p;
}

// ---------------- K0: xsq per batch row; zero counters ----------------
__global__ void k0_prep(const float* __restrict__ x, float* __restrict__ xsq,
                        unsigned* __restrict__ cnt, float* __restrict__ dpos) {
    int t = threadIdx.x;
    if (t < BATCHN) {
        const float4* row = (const float4*)(x + t * FEAT);
        float s = 0.f;
        for (int i = 0; i < FEAT / 4; i++) {
            float4 v = row[i];
            s += v.x * v.x + v.y * v.y + v.z * v.z + v.w * v.w;
        }
        xsq[t] = s;
        cnt[t] = 0u;
        dpos[t] = 0.f;
    }
}

// ---------------- K1: sampled distances (8 Mem rows / block) ----------------
__global__ void k1_sample(const float* __restrict__ x, const float* __restrict__ Mem,
                          const float* __restrict__ xsq, float* __restrict__ samp) {
    __shared__ ushort mrow[8][FEAT];   // bf16-truncated sample rows
    __shared__ float msq[8];
    int t = threadIdx.x;
    int s0 = blockIdx.x * 8;
    {
        int r = t >> 5, c = (t & 31) * 8;
        long mr = (long)(s0 + r) * SSTRIDE;
        if (mr >= MEMN) mr -= MEMN;        // wrap: keep sample in-bounds
        const uint4* mp = (const uint4*)(Mem + mr * FEAT + c);
        uint4 u0 = mp[0], u1 = mp[1];
        *(uint4*)(&mrow[r][c]) = pack8(u0, u1);
    }
    __syncthreads();
    if (t < 8) {
        float s = 0.f;
        for (int k = 0; k < FEAT; k++) { float a = bf2f(mrow[t][k]); s += a * a; }
        msq[t] = s;
    }
    __syncthreads();
    for (int q = 0; q < 4; q++) {
        int pair = t + q * 256;
        int sl = pair >> 7, b = pair & 127;
        const float4* xr = (const float4*)(x + b * FEAT);
        float dot = 0.f;
        for (int i = 0; i < FEAT / 8; i++) {
            float4 x0 = xr[2 * i], x1 = xr[2 * i + 1];
            uint4 mv = *(const uint4*)(&mrow[sl][i * 8]);
            unsigned mw[4] = {mv.x, mv.y, mv.z, mv.w};
            float xf[8] = {x0.x, x0.y, x0.z, x0.w, x1.x, x1.y, x1.z, x1.w};
            for (int j = 0; j < 4; j++) {
                dot += xf[2 * j]     * bf2f(mw[j] & 0xffffu)
                     + xf[2 * j + 1] * bf2f(mw[j] >> 16);
            }
        }
        float d = xsq[b] + msq[sl] - 2.f * dot;
        samp[b * SAMP + (s0 + sl)] = d;
    }
}

// ---------------- K2: per-row cutoff from sample histogram ----------------
__global__ void k2_cutoff(const float* __restrict__ samp, float* __restrict__ cutoff) {
    __shared__ unsigned hist[2048];
    __shared__ unsigned part[256];
    int t = threadIdx.x, b = blockIdx.x;
    for (int i = t; i < 2048; i += 256) hist[i] = 0;
    __syncthreads();
    for (int i = t; i < SAMP; i += 256) {
        float d = samp[b * SAMP + i];
        int bin = (int)(d * 2.f);
        bin = bin < 0 ? 0 : (bin > 2047 ? 2047 : bin);
        atomicAdd(&hist[bin], 1u);
    }
    __syncthreads();
    unsigned p = 0;
    for (int j = 0; j < 8; j++) p += hist[t * 8 + j];
    part[t] = p;
    __syncthreads();
    if (t == 0) {
        const unsigned tgt = 98;  // ~1.2% of 8192 -> ~6000 candidates of 500000
        unsigned cum = 0; int binsel = 2047;
        for (int i = 0; i < 256; i++) {
            if (cum + part[i] >= tgt) {
                for (int j = 0; j < 8; j++) {
                    int bb = i * 8 + j;
                    cum += hist[bb];
                    if (cum >= tgt) { binsel = bb; break; }
                }
                break;
            }
            cum += part[i];
        }
        cutoff[b] = (binsel + 1) * 0.5f + 1.0f;
    }
}

// ---------------- K3: main MFMA GEMM + filtered append ----------------
// v5: revert to the v2 single-buffer structure (explicit pipelining was a
//     measured loss: implicit wave TLP already overlaps). Lever this round:
//     512-thread blocks (8 waves) sharing ONE 64KB xs tile -> same 80.4KB LDS,
//     2 blocks/CU = 16 waves/CU = 4 waves/SIMD (2x the latency hiding of v2).
//     Tile = 128 Mem rows, wave w owns rows w*16..w*16+15.
__launch_bounds__(512, 4)
__global__ void k3_gemm(const float* __restrict__ x, const float* __restrict__ Mem,
                        const int* __restrict__ labels,
                        const float* __restrict__ xsq, const float* __restrict__ cutoff,
                        unsigned* __restrict__ cnt, float* __restrict__ buf,
                        float* __restrict__ dpos) {
    __shared__ ushort xs[BATCHN * FEAT];        // 64 KiB, 16B-chunk XOR swizzle
    __shared__ float cbuf[BATCHN * LCAP];       // 14 KiB candidate staging
    __shared__ unsigned ccnt[BATCHN];           // 512 B
    int t = threadIdx.x;
    if (t < BATCHN) ccnt[t] = 0u;
    // stage whole x (128x256) into LDS as bf16; chunk' = chunk ^ (row&7)
    for (int i = 0; i < 8; i++) {
        int c = i * 512 + t;               // 8-float chunk id, < 4096
        int row = c >> 5, cc = c & 31;
        int ccs = cc ^ (row & 7);
        const uint4* xp = (const uint4*)(x + row * FEAT + cc * 8);
        uint4 u0 = xp[0], u1 = xp[1];
        *(uint4*)(&xs[row * FEAT + ccs * 8]) = pack8(u0, u1);
    }
    int lane = t & 63, wave = t >> 6;       // wave in [0,8)
    int l15 = lane & 15, quad = lane >> 4;
    int rx = l15 & 7;                       // read-side swizzle key (row&7)
    float xsq_v[8], cut_v[8];
    int lab_v[8];
#pragma unroll
    for (int nt = 0; nt < 8; nt++) {
        int b = nt * 16 + l15;
        xsq_v[nt] = xsq[b];
        cut_v[nt] = cutoff[b];
        lab_v[nt] = labels[b];
    }
    __syncthreads();

    for (int tile = blockIdx.x; tile < NTILES; tile += gridDim.x) {
        int mbase = tile * TILE_ROWS + wave * 16;
        int m0 = mbase + l15;
        long mA = m0 < MEMN ? m0 : (MEMN - 1);
        const float* aptr = Mem + mA * FEAT + quad * 8;
        // ---- issue ALL 16 global loads for this wave's 16 rows up front ----
        uint4 ua[8], ub[8];
#pragma unroll
        for (int ks = 0; ks < 8; ks++) {
            const uint4* ap = (const uint4*)(aptr + ks * 32);
            ua[ks] = ap[0];
            ub[ks] = ap[1];
        }
        float4v acc[8];
#pragma unroll
        for (int nt = 0; nt < 8; nt++) acc[nt] = (float4v){0.f, 0.f, 0.f, 0.f};
        float msqp = 0.f;
#pragma unroll
        for (int ks = 0; ks < 8; ks++) {
            float4 f0 = __builtin_bit_cast(float4, ua[ks]);
            float4 f1 = __builtin_bit_cast(float4, ub[ks]);
            msqp += f0.x * f0.x + f0.y * f0.y + f0.z * f0.z + f0.w * f0.w
                  + f1.x * f1.x + f1.y * f1.y + f1.z * f1.z + f1.w * f1.w;
            uint4 av = pack8(ua[ks], ub[ks]);
            bf16x8 af = __builtin_bit_cast(bf16x8, av);
            int ch = ks * 4 + quad;
#pragma unroll
            for (int nt = 0; nt < 8; nt++) {
                uint4 bv = *(const uint4*)(&xs[(nt * 16 + l15) * FEAT + (ch ^ rx) * 8]);
                bf16x8 bfr = __builtin_bit_cast(bf16x8, bv);
                acc[nt] = __builtin_amdgcn_mfma_f32_16x16x32_bf16(af, bfr, acc[nt], 0, 0, 0);
            }
        }
        // reduce msq across the 4 quads: every lane then holds msq[m = mbase + l15]
        float msqf = msqp;
        msqf += __shfl_xor(msqf, 16, 64);
        msqf += __shfl_xor(msqf, 32, 64);
#pragma unroll
        for (int r = 0; r < 4; r++) {
            float msq_r = __shfl(msqf, quad * 4 + r, 64);  // msq of D-row quad*4+r
            int mg = mbase + quad * 4 + r;
            if (mg < MEMN) {
#pragma unroll
                for (int nt = 0; nt < 8; nt++) {
                    float d = xsq_v[nt] + msq_r - 2.f * acc[nt][r];
                    int b = nt * 16 + l15;
                    if (lab_v[nt] == mg) {
                        dpos[b] = d;
                    } else if (d < cut_v[nt]) {
                        unsigned p = atomicAdd(&ccnt[b], 1u);   // LDS atomic: cheap
                        if (p < LCAP) {
                            cbuf[b * LCAP + p] = d;
                        } else {                                // rare overflow path
                            unsigned q = atomicAdd(&cnt[b], 1u);
                            if (q < CAP) buf[(long)b * CAP + q] = d;
                        }
                    }
                }
            }
        }
    }
    // ---- block-end flush: one global atomic per (block, b) ----
    __syncthreads();
    if (t < BATCHN) {
        unsigned nb = ccnt[t];
        if (nb > LCAP) nb = LCAP;
        if (nb) {
            unsigned p = atomicAdd(&cnt[t], nb);
            for (unsigned i = 0; i < nb; i++) {
                unsigned q = p + i;
                if (q < CAP) buf[(long)t * CAP + q] = cbuf[t * LCAP + i];
            }
        }
    }
}

// ---------------- K4: exact per-row selection of k-1 smallest ----------------
__global__ void k4_select(const float* __restrict__ buf, const unsigned* __restrict__ cnt,
                          const float* __restrict__ cutoff, const float* __restrict__ dpos,
                          const int* __restrict__ topk, float* __restrict__ tri) {
    __shared__ unsigned hist[2048];
    __shared__ unsigned part[256];
    __shared__ float coll[1024];
    __shared__ unsigned ncoll;
    __shared__ int sTb;
    __shared__ unsigned sC1;
    __shared__ float wsum[4];
    int t = threadIdx.x, b = blockIdx.x;
    int k1 = topk[0] - 1;
    unsigned c = cnt[b]; if (c > CAP) c = CAP;
    float invw = 2048.f / cutoff[b];
    for (int i = t; i < 2048; i += 256) hist[i] = 0;
    if (t == 0) ncoll = 0;
    __syncthreads();
    const float* vals = buf + (long)b * CAP;
    for (unsigned i = t; i < c; i += 256) {
        float d = vals[i];
        int bin = (int)(d * invw);
        bin = bin < 0 ? 0 : (bin > 2047 ? 2047 : bin);
        atomicAdd(&hist[bin], 1u);
    }
    __syncthreads();
    unsigned p = 0;
    for (int j = 0; j < 8; j++) p += hist[t * 8 + j];
    part[t] = p;
    __syncthreads();
    if (t == 0) {
        unsigned tgt = (c < (unsigned)k1) ? c : (unsigned)k1;
        unsigned cum = 0; int Tb = 2048; unsigned C1 = 0;
        if (tgt > 0) {
            for (int i = 0; i < 256; i++) {
                if (cum + part[i] >= tgt) {
                    for (int j = 0; j < 8; j++) {
                        int bb = i * 8 + j;
                        if (cum + hist[bb] >= tgt) { Tb = bb; C1 = cum; break; }
                        cum += hist[bb];
                    }
                    break;
                }
                cum += part[i];
            }
        }
        sTb = Tb; sC1 = C1;
    }
    __syncthreads();
    int Tb = sTb; unsigned C1 = sC1;
    float ls = 0.f;
    for (unsigned i = t; i < c; i += 256) {
        float d = vals[i];
        int bin = (int)(d * invw);
        bin = bin < 0 ? 0 : (bin > 2047 ? 2047 : bin);
        if (bin < Tb) ls += d;
        else if (bin == Tb) {
            unsigned ix = atomicAdd(&ncoll, 1u);
            if (ix < 1024) coll[ix] = d;
        }
    }
    ls += __shfl_down(ls, 32, 64); ls += __shfl_down(ls, 16, 64);
    ls += __shfl_down(ls, 8, 64);  ls += __shfl_down(ls, 4, 64);
    ls += __shfl_down(ls, 2, 64);  ls += __shfl_down(ls, 1, 64);
    if ((t & 63) == 0) wsum[t >> 6] = ls;
    __syncthreads();
    if (t == 0) {
        float S = wsum[0] + wsum[1] + wsum[2] + wsum[3];
        unsigned tgt = (c < (unsigned)k1) ? c : (unsigned)k1;
        int r = (int)(tgt - C1);
        unsigned nc = ncoll; if (nc > 1024) nc = 1024;
        for (int i = 0; i < r && i < (int)nc; i++) {
            float mn = 3.4e38f; int mi = 0;
            for (unsigned j = 0; j < nc; j++) if (coll[j] < mn) { mn = coll[j]; mi = (int)j; }
            S += mn; coll[mi] = 3.4e38f;
        }
        float minl = dpos[b];
        minl = minl < 1e-12f ? 1e-12f : (minl > 1e12f ? 1e12f : minl);
        minl += (float)(MEMN - 1) * 1e-12f;  // clip() lifts the M-1 zeros to 1e-12
        float maxl = S / (float)k1;
        float loss = minl - maxl + 1.0f; if (loss < 0.f) loss = 0.f;
        tri[b * 3 + 0] = loss; tri[b * 3 + 1] = minl; tri[b * 3 + 2] = maxl;
    }
}

// ---------------- K5: means -> 3 fp32 outputs ----------------
__global__ void k5_final(const float* __restrict__ tri, float* __restrict__ out) {
    __shared__ float ws2[6];
    int t = threadIdx.x;  // 128 threads
    float l = tri[t * 3 + 0], mi = tri[t * 3 + 1], mx = tri[t * 3 + 2];
    for (int s = 32; s >= 1; s >>= 1) {
        l += __shfl_down(l, s, 64);
        mi += __shfl_down(mi, s, 64);
        mx += __shfl_down(mx, s, 64);
    }
    if ((t & 63) == 0) { int wv = t >> 6; ws2[wv * 3 + 0] = l; ws2[wv * 3 + 1] = mi; ws2[wv * 3 + 2] = mx; }
    __syncthreads();
    if (t == 0) {
        out[0] = (ws2[0] + ws2[3]) * (1.f / 128.f);
        out[1] = (ws2[1] + ws2[4]) * (1.f / 128.f);
        out[2] = (ws2[2] + ws2[5]) * (1.f / 128.f);
    }
}

__global__ void k_sentinel(float* out) {
    out[0] = -777.f; out[1] = -777.f; out[2] = -777.f;
}

extern "C" void kernel_launch(void* const* d_in, const int* in_sizes, int n_in,
                              void* d_out, int out_size, void* d_ws, size_t ws_size,
                              hipStream_t stream) {
    const float* x     = (const float*)d_in[0];
    const int* labels  = (const int*)d_in[1];
    const float* Mem   = (const float*)d_in[2];
    const int* topk    = (const int*)d_in[3];
    (void)in_sizes; (void)n_in; (void)out_size;

    char* ws = (char*)d_ws;
    const size_t OFF_SAMP = 0;                       // 128*8192*4 = 4 MiB
    const size_t OFF_BUF  = 4194304;                 // 128*16384*4 = 8 MiB
    const size_t OFF_CNT  = OFF_BUF + 8388608;
    const size_t OFF_XSQ  = OFF_CNT + 512;
    const size_t OFF_DPOS = OFF_XSQ + 512;
    const size_t OFF_CUT  = OFF_DPOS + 512;
    const size_t OFF_TRI  = OFF_CUT + 512;
    const size_t NEEDED   = OFF_TRI + 1536;
    if (ws_size < NEEDED) {
        k_sentinel<<<1, 1, 0, stream>>>((float*)d_out);
        return;
    }
    float*    samp   = (float*)(ws + OFF_SAMP);
    float*    buf    = (float*)(ws + OFF_BUF);
    unsigned* cnt    = (unsigned*)(ws + OFF_CNT);
    float*    xsq    = (float*)(ws + OFF_XSQ);
    float*    dpos   = (float*)(ws + OFF_DPOS);
    float*    cutoff = (float*)(ws + OFF_CUT);
    float*    tri    = (float*)(ws + OFF_TRI);

    k0_prep  <<<1,      128, 0, stream>>>(x, xsq, cnt, dpos);
    k1_sample<<<1024,   256, 0, stream>>>(x, Mem, xsq, samp);
    k2_cutoff<<<128,    256, 0, stream>>>(samp, cutoff);
    k3_gemm  <<<K3GRID, 512, 0, stream>>>(x, Mem, labels, xsq, cutoff, cnt, buf, dpos);
    k4_select<<<128,    256, 0, stream>>>(buf, cnt, cutoff, dpos, topk, tri);
    k5_final <<<1,      128, 0, stream>>>(tri, (float*)d_out);
}

// Round 5
// 875.635 us; speedup vs baseline: 1.3052x; 1.0103x over previous
//
#include <hip/hip_runtime.h>
#include <hip/hip_bf16.h>
#include <stdint.h>

#define MEMN 500000
#define FEAT 256
#define BATCHN 128
#define SAMP 8192
#define SSTRIDE 61
#define CAP 16384
#define LCAP 16
#define TILE_ROWS 128
#define NTILES ((MEMN + TILE_ROWS - 1) / TILE_ROWS)
#define K3GRID 1024

typedef __bf16 bf16x8 __attribute__((ext_vector_type(8)));
typedef float float4v __attribute__((ext_vector_type(4)));

__device__ __forceinline__ float bf2f(unsigned bits) {
    return __uint_as_float(bits << 16);
}

// pack 8 fp32 (two uint4 views) -> 8 bf16 by truncation
__device__ __forceinline__ uint4 pack8(const uint4 u0, const uint4 u1) {
    uint4 p;
    p.x = (u0.y & 0xffff0000u) | (u0.x >> 16);
    p.y = (u0.w & 0xffff0000u) | (u0.z >> 16);
    p.z = (u1.y & 0xffff0000u) | (u1.x >> 16);
    p.w = (u1.w & 0xffff0000u) | (u1.z >> 16);
    return p;
}

// ---------------- K1: sampled PARTIAL distances (8 Mem rows / block) --------
// Block SAMP/8 (==1024) is the prep block: xsq per batch row, zero counters,
// zero the 3 output accumulators (k4 atomicAdds into them).
// Sample blocks store d_partial = msq - 2*dot (no xsq -> no k0 dependency);
// k2 adds xsq[b] when binning.
__global__ void k1_sample(const float* __restrict__ x, const float* __restrict__ Mem,
                          float* __restrict__ xsq, unsigned* __restrict__ cnt,
                          float* __restrict__ dpos, float* __restrict__ out,
                          float* __restrict__ samp) {
    int t = threadIdx.x;
    if (blockIdx.x == SAMP / 8) {
        // ---- prep block (replaces old k0) ----
        if (t < BATCHN) {
            const float4* row = (const float4*)(x + t * FEAT);
            float s = 0.f;
            for (int i = 0; i < FEAT / 4; i++) {
                float4 v = row[i];
                s += v.x * v.x + v.y * v.y + v.z * v.z + v.w * v.w;
            }
            xsq[t] = s;
            cnt[t] = 0u;
            dpos[t] = 0.f;
        }
        if (t >= BATCHN && t < BATCHN + 3) out[t - BATCHN] = 0.f;
        return;
    }
    __shared__ ushort mrow[8][FEAT];   // bf16-truncated sample rows
    __shared__ float msq[8];
    int s0 = blockIdx.x * 8;
    {
        int r = t >> 5, c = (t & 31) * 8;
        long mr = (long)(s0 + r) * SSTRIDE;
        if (mr >= MEMN) mr -= MEMN;        // wrap: keep sample in-bounds
        const uint4* mp = (const uint4*)(Mem + mr * FEAT + c);
        uint4 u0 = mp[0], u1 = mp[1];
        *(uint4*)(&mrow[r][c]) = pack8(u0, u1);
    }
    __syncthreads();
    if (t < 8) {
        float s = 0.f;
        for (int k = 0; k < FEAT; k++) { float a = bf2f(mrow[t][k]); s += a * a; }
        msq[t] = s;
    }
    __syncthreads();
    for (int q = 0; q < 4; q++) {
        int pair = t + q * 256;
        int sl = pair >> 7, b = pair & 127;
        const float4* xr = (const float4*)(x + b * FEAT);
        float dot = 0.f;
        for (int i = 0; i < FEAT / 8; i++) {
            float4 x0 = xr[2 * i], x1 = xr[2 * i + 1];
            uint4 mv = *(const uint4*)(&mrow[sl][i * 8]);
            unsigned mw[4] = {mv.x, mv.y, mv.z, mv.w};
            float xf[8] = {x0.x, x0.y, x0.z, x0.w, x1.x, x1.y, x1.z, x1.w};
            for (int j = 0; j < 4; j++) {
                dot += xf[2 * j]     * bf2f(mw[j] & 0xffffu)
                     + xf[2 * j + 1] * bf2f(mw[j] >> 16);
            }
        }
        float d = msq[sl] - 2.f * dot;          // partial: xsq added in k2
        samp[b * SAMP + (s0 + sl)] = d;
    }
}

// ---------------- K2: per-row cutoff from sample histogram ----------------
__global__ void k2_cutoff(const float* __restrict__ samp, const float* __restrict__ xsq,
                          float* __restrict__ cutoff) {
    __shared__ unsigned hist[2048];
    __shared__ unsigned part[256];
    int t = threadIdx.x, b = blockIdx.x;
    float xb = xsq[b];
    for (int i = t; i < 2048; i += 256) hist[i] = 0;
    __syncthreads();
    for (int i = t; i < SAMP; i += 256) {
        float d = samp[b * SAMP + i] + xb;
        int bin = (int)(d * 2.f);
        bin = bin < 0 ? 0 : (bin > 2047 ? 2047 : bin);
        atomicAdd(&hist[bin], 1u);
    }
    __syncthreads();
    unsigned p = 0;
    for (int j = 0; j < 8; j++) p += hist[t * 8 + j];
    part[t] = p;
    __syncthreads();
    if (t == 0) {
        const unsigned tgt = 98;  // ~1.2% of 8192 -> ~6000 candidates of 500000
        unsigned cum = 0; int binsel = 2047;
        for (int i = 0; i < 256; i++) {
            if (cum + part[i] >= tgt) {
                for (int j = 0; j < 8; j++) {
                    int bb = i * 8 + j;
                    cum += hist[bb];
                    if (cum >= tgt) { binsel = bb; break; }
                }
                break;
            }
            cum += part[i];
        }
        cutoff[b] = (binsel + 1) * 0.5f + 1.0f;
    }
}

// ---------------- K3: main MFMA GEMM + filtered append ----------------
// v6: same structure as v5 (single-buffer, 512 threads, 8 waves sharing one
//     64KB xs tile). Lever: LCAP 28->16 shrinks LDS 80384->74240 B so
//     2 blocks/CU (16 waves/CU) is GUARANTEED even with driver LDS reserve --
//     v5's 2x80384=160768 of 163840 was within 3KB of the limit and may have
//     silently dropped to 1 block/CU. Overflow path keeps correctness exact.
__launch_bounds__(512, 4)
__global__ void k3_gemm(const float* __restrict__ x, const float* __restrict__ Mem,
                        const int* __restrict__ labels,
                        const float* __restrict__ xsq, const float* __restrict__ cutoff,
                        unsigned* __restrict__ cnt, float* __restrict__ buf,
                        float* __restrict__ dpos) {
    __shared__ ushort xs[BATCHN * FEAT];        // 64 KiB, 16B-chunk XOR swizzle
    __shared__ float cbuf[BATCHN * LCAP];       // 8 KiB candidate staging
    __shared__ unsigned ccnt[BATCHN];           // 512 B
    int t = threadIdx.x;
    if (t < BATCHN) ccnt[t] = 0u;
    // stage whole x (128x256) into LDS as bf16; chunk' = chunk ^ (row&7)
    for (int i = 0; i < 8; i++) {
        int c = i * 512 + t;               // 8-float chunk id, < 4096
        int row = c >> 5, cc = c & 31;
        int ccs = cc ^ (row & 7);
        const uint4* xp = (const uint4*)(x + row * FEAT + cc * 8);
        uint4 u0 = xp[0], u1 = xp[1];
        *(uint4*)(&xs[row * FEAT + ccs * 8]) = pack8(u0, u1);
    }
    int lane = t & 63, wave = t >> 6;       // wave in [0,8)
    int l15 = lane & 15, quad = lane >> 4;
    int rx = l15 & 7;                       // read-side swizzle key (row&7)
    float xsq_v[8], cut_v[8];
    int lab_v[8];
#pragma unroll
    for (int nt = 0; nt < 8; nt++) {
        int b = nt * 16 + l15;
        xsq_v[nt] = xsq[b];
        cut_v[nt] = cutoff[b];
        lab_v[nt] = labels[b];
    }
    __syncthreads();

    for (int tile = blockIdx.x; tile < NTILES; tile += gridDim.x) {
        int mbase = tile * TILE_ROWS + wave * 16;
        int m0 = mbase + l15;
        long mA = m0 < MEMN ? m0 : (MEMN - 1);
        const float* aptr = Mem + mA * FEAT + quad * 8;
        // ---- issue ALL 16 global loads for this wave's 16 rows up front ----
        uint4 ua[8], ub[8];
#pragma unroll
        for (int ks = 0; ks < 8; ks++) {
            const uint4* ap = (const uint4*)(aptr + ks * 32);
            ua[ks] = ap[0];
            ub[ks] = ap[1];
        }
        float4v acc[8];
#pragma unroll
        for (int nt = 0; nt < 8; nt++) acc[nt] = (float4v){0.f, 0.f, 0.f, 0.f};
        float msqp = 0.f;
#pragma unroll
        for (int ks = 0; ks < 8; ks++) {
            float4 f0 = __builtin_bit_cast(float4, ua[ks]);
            float4 f1 = __builtin_bit_cast(float4, ub[ks]);
            msqp += f0.x * f0.x + f0.y * f0.y + f0.z * f0.z + f0.w * f0.w
                  + f1.x * f1.x + f1.y * f1.y + f1.z * f1.z + f1.w * f1.w;
            uint4 av = pack8(ua[ks], ub[ks]);
            bf16x8 af = __builtin_bit_cast(bf16x8, av);
            int ch = ks * 4 + quad;
#pragma unroll
            for (int nt = 0; nt < 8; nt++) {
                uint4 bv = *(const uint4*)(&xs[(nt * 16 + l15) * FEAT + (ch ^ rx) * 8]);
                bf16x8 bfr = __builtin_bit_cast(bf16x8, bv);
                acc[nt] = __builtin_amdgcn_mfma_f32_16x16x32_bf16(af, bfr, acc[nt], 0, 0, 0);
            }
        }
        // reduce msq across the 4 quads: every lane then holds msq[m = mbase + l15]
        float msqf = msqp;
        msqf += __shfl_xor(msqf, 16, 64);
        msqf += __shfl_xor(msqf, 32, 64);
#pragma unroll
        for (int r = 0; r < 4; r++) {
            float msq_r = __shfl(msqf, quad * 4 + r, 64);  // msq of D-row quad*4+r
            int mg = mbase + quad * 4 + r;
            if (mg < MEMN) {
#pragma unroll
                for (int nt = 0; nt < 8; nt++) {
                    float d = xsq_v[nt] + msq_r - 2.f * acc[nt][r];
                    int b = nt * 16 + l15;
                    if (lab_v[nt] == mg) {
                        dpos[b] = d;
                    } else if (d < cut_v[nt]) {
                        unsigned p = atomicAdd(&ccnt[b], 1u);   // LDS atomic: cheap
                        if (p < LCAP) {
                            cbuf[b * LCAP + p] = d;
                        } else {                                // rare overflow path
                            unsigned q = atomicAdd(&cnt[b], 1u);
                            if (q < CAP) buf[(long)b * CAP + q] = d;
                        }
                    }
                }
            }
        }
    }
    // ---- block-end flush: one global atomic per (block, b) ----
    __syncthreads();
    if (t < BATCHN) {
        unsigned nb = ccnt[t];
        if (nb > LCAP) nb = LCAP;
        if (nb) {
            unsigned p = atomicAdd(&cnt[t], nb);
            for (unsigned i = 0; i < nb; i++) {
                unsigned q = p + i;
                if (q < CAP) buf[(long)t * CAP + q] = cbuf[t * LCAP + i];
            }
        }
    }
}

// ---------------- K4: exact per-row selection + final means ----------------
// v6: folds old k5 -- each block atomicAdds its loss/min/max contribution
//     into out[0..2] (zeroed by k1's prep block).
__global__ void k4_select(const float* __restrict__ buf, const unsigned* __restrict__ cnt,
                          const float* __restrict__ cutoff, const float* __restrict__ dpos,
                          const int* __restrict__ topk, float* __restrict__ out) {
    __shared__ unsigned hist[2048];
    __shared__ unsigned part[256];
    __shared__ float coll[1024];
    __shared__ unsigned ncoll;
    __shared__ int sTb;
    __shared__ unsigned sC1;
    __shared__ float wsum[4];
    int t = threadIdx.x, b = blockIdx.x;
    int k1 = topk[0] - 1;
    unsigned c = cnt[b]; if (c > CAP) c = CAP;
    float invw = 2048.f / cutoff[b];
    for (int i = t; i < 2048; i += 256) hist[i] = 0;
    if (t == 0) ncoll = 0;
    __syncthreads();
    const float* vals = buf + (long)b * CAP;
    for (unsigned i = t; i < c; i += 256) {
        float d = vals[i];
        int bin = (int)(d * invw);
        bin = bin < 0 ? 0 : (bin > 2047 ? 2047 : bin);
        atomicAdd(&hist[bin], 1u);
    }
    __syncthreads();
    unsigned p = 0;
    for (int j = 0; j < 8; j++) p += hist[t * 8 + j];
    part[t] = p;
    __syncthreads();
    if (t == 0) {
        unsigned tgt = (c < (unsigned)k1) ? c : (unsigned)k1;
        unsigned cum = 0; int Tb = 2048; unsigned C1 = 0;
        if (tgt > 0) {
            for (int i = 0; i < 256; i++) {
                if (cum + part[i] >= tgt) {
                    for (int j = 0; j < 8; j++) {
                        int bb = i * 8 + j;
                        if (cum + hist[bb] >= tgt) { Tb = bb; C1 = cum; break; }
                        cum += hist[bb];
                    }
                    break;
                }
                cum += part[i];
            }
        }
        sTb = Tb; sC1 = C1;
    }
    __syncthreads();
    int Tb = sTb; unsigned C1 = sC1;
    float ls = 0.f;
    for (unsigned i = t; i < c; i += 256) {
        float d = vals[i];
        int bin = (int)(d * invw);
        bin = bin < 0 ? 0 : (bin > 2047 ? 2047 : bin);
        if (bin < Tb) ls += d;
        else if (bin == Tb) {
            unsigned ix = atomicAdd(&ncoll, 1u);
            if (ix < 1024) coll[ix] = d;
        }
    }
    ls += __shfl_down(ls, 32, 64); ls += __shfl_down(ls, 16, 64);
    ls += __shfl_down(ls, 8, 64);  ls += __shfl_down(ls, 4, 64);
    ls += __shfl_down(ls, 2, 64);  ls += __shfl_down(ls, 1, 64);
    if ((t & 63) == 0) wsum[t >> 6] = ls;
    __syncthreads();
    if (t == 0) {
        float S = wsum[0] + wsum[1] + wsum[2] + wsum[3];
        unsigned tgt = (c < (unsigned)k1) ? c : (unsigned)k1;
        int r = (int)(tgt - C1);
        unsigned nc = ncoll; if (nc > 1024) nc = 1024;
        for (int i = 0; i < r && i < (int)nc; i++) {
            float mn = 3.4e38f; int mi = 0;
            for (unsigned j = 0; j < nc; j++) if (coll[j] < mn) { mn = coll[j]; mi = (int)j; }
            S += mn; coll[mi] = 3.4e38f;
        }
        float minl = dpos[b];
        minl = minl < 1e-12f ? 1e-12f : (minl > 1e12f ? 1e12f : minl);
        minl += (float)(MEMN - 1) * 1e-12f;  // clip() lifts the M-1 zeros to 1e-12
        float maxl = S / (float)k1;
        float loss = minl - maxl + 1.0f; if (loss < 0.f) loss = 0.f;
        atomicAdd(&out[0], loss * (1.f / 128.f));
        atomicAdd(&out[1], minl * (1.f / 128.f));
        atomicAdd(&out[2], maxl * (1.f / 128.f));
    }
}

__global__ void k_sentinel(float* out) {
    out[0] = -777.f; out[1] = -777.f; out[2] = -777.f;
}

extern "C" void kernel_launch(void* const* d_in, const int* in_sizes, int n_in,
                              void* d_out, int out_size, void* d_ws, size_t ws_size,
                              hipStream_t stream) {
    const float* x     = (const float*)d_in[0];
    const int* labels  = (const int*)d_in[1];
    const float* Mem   = (const float*)d_in[2];
    const int* topk    = (const int*)d_in[3];
    (void)in_sizes; (void)n_in; (void)out_size;

    char* ws = (char*)d_ws;
    const size_t OFF_SAMP = 0;                       // 128*8192*4 = 4 MiB
    const size_t OFF_BUF  = 4194304;                 // 128*16384*4 = 8 MiB
    const size_t OFF_CNT  = OFF_BUF + 8388608;
    const size_t OFF_XSQ  = OFF_CNT + 512;
    const size_t OFF_DPOS = OFF_XSQ + 512;
    const size_t OFF_CUT  = OFF_DPOS + 512;
    const size_t NEEDED   = OFF_CUT + 512;
    if (ws_size < NEEDED) {
        k_sentinel<<<1, 1, 0, stream>>>((float*)d_out);
        return;
    }
    float*    samp   = (float*)(ws + OFF_SAMP);
    float*    buf    = (float*)(ws + OFF_BUF);
    unsigned* cnt    = (unsigned*)(ws + OFF_CNT);
    float*    xsq    = (float*)(ws + OFF_XSQ);
    float*    dpos   = (float*)(ws + OFF_DPOS);
    float*    cutoff = (float*)(ws + OFF_CUT);

    k1_sample<<<SAMP / 8 + 1, 256, 0, stream>>>(x, Mem, xsq, cnt, dpos,
                                                (float*)d_out, samp);
    k2_cutoff<<<128,    256, 0, stream>>>(samp, xsq, cutoff);
    k3_gemm  <<<K3GRID, 512, 0, stream>>>(x, Mem, labels, xsq, cutoff, cnt, buf, dpos);
    k4_select<<<128,    256, 0, stream>>>(buf, cnt, cutoff, dpos, topk, (float*)d_out);
}

// Round 6
// 743.823 us; speedup vs baseline: 1.5365x; 1.1772x over previous
//
#include <hip/hip_runtime.h>
#include <hip/hip_bf16.h>
#include <stdint.h>

#define MEMN 500000
#define FEAT 256
#define BATCHN 128
#define SAMP 8192
#define SSTRIDE 61
#define CAP 16384
#define LCAP 16
#define TILE_ROWS 128
#define NTILES ((MEMN + TILE_ROWS - 1) / TILE_ROWS)
#define K3GRID 1024

typedef __bf16 bf16x8 __attribute__((ext_vector_type(8)));
typedef float float4v __attribute__((ext_vector_type(4)));

__device__ __forceinline__ float bf2f(unsigned bits) {
    return __uint_as_float(bits << 16);
}

// pack 8 fp32 (two uint4 views) -> 8 bf16 by truncation
__device__ __forceinline__ uint4 pack8(const uint4 u0, const uint4 u1) {
    uint4 p;
    p.x = (u0.y & 0xffff0000u) | (u0.x >> 16);
    p.y = (u0.w & 0xffff0000u) | (u0.z >> 16);
    p.z = (u1.y & 0xffff0000u) | (u1.x >> 16);
    p.w = (u1.w & 0xffff0000u) | (u1.z >> 16);
    return p;
}

// ---------------- K1: sampled partial distances via MFMA ----------------
// v7: k1 is now a 64-tile copy of k3's verified MFMA structure over the
//     8192 sampled Mem rows (row = s*61 <= 499651, always in-bounds).
//     Stores d_partial = msq - 2*dot TRANSPOSED: samp[s*128 + b] (coalesced
//     64B segments); k2 adds xsq[b] at binning. Block 64 = prep block
//     (xsq, zero cnt/dpos/out) -- replaces old k0/k5.
__launch_bounds__(512, 4)
__global__ void k1_sample(const float* __restrict__ x, const float* __restrict__ Mem,
                          float* __restrict__ xsq, unsigned* __restrict__ cnt,
                          float* __restrict__ dpos, float* __restrict__ out,
                          float* __restrict__ samp) {
    int t = threadIdx.x;
    if (blockIdx.x == SAMP / TILE_ROWS) {
        // ---- prep block ----
        if (t < BATCHN) {
            const float4* row = (const float4*)(x + t * FEAT);
            float s = 0.f;
            for (int i = 0; i < FEAT / 4; i++) {
                float4 v = row[i];
                s += v.x * v.x + v.y * v.y + v.z * v.z + v.w * v.w;
            }
            xsq[t] = s;
            cnt[t] = 0u;
            dpos[t] = 0.f;
        }
        if (t >= BATCHN && t < BATCHN + 3) out[t - BATCHN] = 0.f;
        return;
    }
    __shared__ ushort xs[BATCHN * FEAT];        // 64 KiB, 16B-chunk XOR swizzle
    // stage whole x (128x256) into LDS as bf16; chunk' = chunk ^ (row&7)
    for (int i = 0; i < 8; i++) {
        int c = i * 512 + t;
        int row = c >> 5, cc = c & 31;
        int ccs = cc ^ (row & 7);
        const uint4* xp = (const uint4*)(x + row * FEAT + cc * 8);
        uint4 u0 = xp[0], u1 = xp[1];
        *(uint4*)(&xs[row * FEAT + ccs * 8]) = pack8(u0, u1);
    }
    int lane = t & 63, wave = t >> 6;
    int l15 = lane & 15, quad = lane >> 4;
    int rx = l15 & 7;
    __syncthreads();

    int sbase = blockIdx.x * TILE_ROWS + wave * 16;   // sample-slot base, <8192
    long mrow = (long)(sbase + l15) * SSTRIDE;        // Mem row, always < MEMN
    const float* aptr = Mem + mrow * FEAT + quad * 8;
    uint4 ua[8], ub[8];
#pragma unroll
    for (int ks = 0; ks < 8; ks++) {
        const uint4* ap = (const uint4*)(aptr + ks * 32);
        ua[ks] = ap[0];
        ub[ks] = ap[1];
    }
    float4v acc[8];
#pragma unroll
    for (int nt = 0; nt < 8; nt++) acc[nt] = (float4v){0.f, 0.f, 0.f, 0.f};
    float m0 = 0.f, m1 = 0.f, m2 = 0.f, m3 = 0.f;   // 4 chains, not 1
#pragma unroll
    for (int ks = 0; ks < 8; ks++) {
        float4 f0 = __builtin_bit_cast(float4, ua[ks]);
        float4 f1 = __builtin_bit_cast(float4, ub[ks]);
        m0 += f0.x * f0.x + f0.y * f0.y;
        m1 += f0.z * f0.z + f0.w * f0.w;
        m2 += f1.x * f1.x + f1.y * f1.y;
        m3 += f1.z * f1.z + f1.w * f1.w;
        uint4 av = pack8(ua[ks], ub[ks]);
        bf16x8 af = __builtin_bit_cast(bf16x8, av);
        int ch = ks * 4 + quad;
#pragma unroll
        for (int nt = 0; nt < 8; nt++) {
            uint4 bv = *(const uint4*)(&xs[(nt * 16 + l15) * FEAT + (ch ^ rx) * 8]);
            bf16x8 bfr = __builtin_bit_cast(bf16x8, bv);
            acc[nt] = __builtin_amdgcn_mfma_f32_16x16x32_bf16(af, bfr, acc[nt], 0, 0, 0);
        }
    }
    float msqf = (m0 + m1) + (m2 + m3);
    msqf += __shfl_xor(msqf, 16, 64);
    msqf += __shfl_xor(msqf, 32, 64);
#pragma unroll
    for (int r = 0; r < 4; r++) {
        float msq_r = __shfl(msqf, quad * 4 + r, 64);
        int sg = sbase + quad * 4 + r;
#pragma unroll
        for (int nt = 0; nt < 8; nt++) {
            float dp = msq_r - 2.f * acc[nt][r];     // partial: xsq added in k2
            samp[sg * BATCHN + nt * 16 + l15] = dp;
        }
    }
}

// ---------------- K2: per-row cutoff from sample histogram ----------------
// v7: reads transposed samp[s*128 + b] (L2/L3-resident, 4 MB).
__global__ void k2_cutoff(const float* __restrict__ samp, const float* __restrict__ xsq,
                          float* __restrict__ cutoff) {
    __shared__ unsigned hist[2048];
    __shared__ unsigned part[256];
    int t = threadIdx.x, b = blockIdx.x;
    float xb = xsq[b];
    for (int i = t; i < 2048; i += 256) hist[i] = 0;
    __syncthreads();
    for (int i = t; i < SAMP; i += 256) {
        float d = samp[i * BATCHN + b] + xb;
        int bin = (int)(d * 2.f);
        bin = bin < 0 ? 0 : (bin > 2047 ? 2047 : bin);
        atomicAdd(&hist[bin], 1u);
    }
    __syncthreads();
    unsigned p = 0;
    for (int j = 0; j < 8; j++) p += hist[t * 8 + j];
    part[t] = p;
    __syncthreads();
    if (t == 0) {
        const unsigned tgt = 98;  // ~1.2% of 8192 -> ~6000 candidates of 500000
        unsigned cum = 0; int binsel = 2047;
        for (int i = 0; i < 256; i++) {
            if (cum + part[i] >= tgt) {
                for (int j = 0; j < 8; j++) {
                    int bb = i * 8 + j;
                    cum += hist[bb];
                    if (cum >= tgt) { binsel = bb; break; }
                }
                break;
            }
            cum += part[i];
        }
        cutoff[b] = (binsel + 1) * 0.5f + 1.0f;
    }
}

// ---------------- K3: main MFMA GEMM + filtered append ----------------
// v7: = v6 (512 thr, 2 blocks/CU, LDS append) + msq chain split (4 accs).
__launch_bounds__(512, 4)
__global__ void k3_gemm(const float* __restrict__ x, const float* __restrict__ Mem,
                        const int* __restrict__ labels,
                        const float* __restrict__ xsq, const float* __restrict__ cutoff,
                        unsigned* __restrict__ cnt, float* __restrict__ buf,
                        float* __restrict__ dpos) {
    __shared__ ushort xs[BATCHN * FEAT];        // 64 KiB, 16B-chunk XOR swizzle
    __shared__ float cbuf[BATCHN * LCAP];       // 8 KiB candidate staging
    __shared__ unsigned ccnt[BATCHN];           // 512 B
    int t = threadIdx.x;
    if (t < BATCHN) ccnt[t] = 0u;
    for (int i = 0; i < 8; i++) {
        int c = i * 512 + t;
        int row = c >> 5, cc = c & 31;
        int ccs = cc ^ (row & 7);
        const uint4* xp = (const uint4*)(x + row * FEAT + cc * 8);
        uint4 u0 = xp[0], u1 = xp[1];
        *(uint4*)(&xs[row * FEAT + ccs * 8]) = pack8(u0, u1);
    }
    int lane = t & 63, wave = t >> 6;       // wave in [0,8)
    int l15 = lane & 15, quad = lane >> 4;
    int rx = l15 & 7;
    float xsq_v[8], cut_v[8];
    int lab_v[8];
#pragma unroll
    for (int nt = 0; nt < 8; nt++) {
        int b = nt * 16 + l15;
        xsq_v[nt] = xsq[b];
        cut_v[nt] = cutoff[b];
        lab_v[nt] = labels[b];
    }
    __syncthreads();

    for (int tile = blockIdx.x; tile < NTILES; tile += gridDim.x) {
        int mbase = tile * TILE_ROWS + wave * 16;
        int m0 = mbase + l15;
        long mA = m0 < MEMN ? m0 : (MEMN - 1);
        const float* aptr = Mem + mA * FEAT + quad * 8;
        uint4 ua[8], ub[8];
#pragma unroll
        for (int ks = 0; ks < 8; ks++) {
            const uint4* ap = (const uint4*)(aptr + ks * 32);
            ua[ks] = ap[0];
            ub[ks] = ap[1];
        }
        float4v acc[8];
#pragma unroll
        for (int nt = 0; nt < 8; nt++) acc[nt] = (float4v){0.f, 0.f, 0.f, 0.f};
        float m0s = 0.f, m1s = 0.f, m2s = 0.f, m3s = 0.f;  // 4 chains, not 1
#pragma unroll
        for (int ks = 0; ks < 8; ks++) {
            float4 f0 = __builtin_bit_cast(float4, ua[ks]);
            float4 f1 = __builtin_bit_cast(float4, ub[ks]);
            m0s += f0.x * f0.x + f0.y * f0.y;
            m1s += f0.z * f0.z + f0.w * f0.w;
            m2s += f1.x * f1.x + f1.y * f1.y;
            m3s += f1.z * f1.z + f1.w * f1.w;
            uint4 av = pack8(ua[ks], ub[ks]);
            bf16x8 af = __builtin_bit_cast(bf16x8, av);
            int ch = ks * 4 + quad;
#pragma unroll
            for (int nt = 0; nt < 8; nt++) {
                uint4 bv = *(const uint4*)(&xs[(nt * 16 + l15) * FEAT + (ch ^ rx) * 8]);
                bf16x8 bfr = __builtin_bit_cast(bf16x8, bv);
                acc[nt] = __builtin_amdgcn_mfma_f32_16x16x32_bf16(af, bfr, acc[nt], 0, 0, 0);
            }
        }
        float msqf = (m0s + m1s) + (m2s + m3s);
        msqf += __shfl_xor(msqf, 16, 64);
        msqf += __shfl_xor(msqf, 32, 64);
#pragma unroll
        for (int r = 0; r < 4; r++) {
            float msq_r = __shfl(msqf, quad * 4 + r, 64);
            int mg = mbase + quad * 4 + r;
            if (mg < MEMN) {
#pragma unroll
                for (int nt = 0; nt < 8; nt++) {
                    float d = xsq_v[nt] + msq_r - 2.f * acc[nt][r];
                    int b = nt * 16 + l15;
                    if (lab_v[nt] == mg) {
                        dpos[b] = d;
                    } else if (d < cut_v[nt]) {
                        unsigned p = atomicAdd(&ccnt[b], 1u);   // LDS atomic: cheap
                        if (p < LCAP) {
                            cbuf[b * LCAP + p] = d;
                        } else {                                // rare overflow path
                            unsigned q = atomicAdd(&cnt[b], 1u);
                            if (q < CAP) buf[(long)b * CAP + q] = d;
                        }
                    }
                }
            }
        }
    }
    // ---- block-end flush: one global atomic per (block, b) ----
    __syncthreads();
    if (t < BATCHN) {
        unsigned nb = ccnt[t];
        if (nb > LCAP) nb = LCAP;
        if (nb) {
            unsigned p = atomicAdd(&cnt[t], nb);
            for (unsigned i = 0; i < nb; i++) {
                unsigned q = p + i;
                if (q < CAP) buf[(long)t * CAP + q] = cbuf[t * LCAP + i];
            }
        }
    }
}

// ---------------- K4: exact per-row selection + final means ----------------
__global__ void k4_select(const float* __restrict__ buf, const unsigned* __restrict__ cnt,
                          const float* __restrict__ cutoff, const float* __restrict__ dpos,
                          const int* __restrict__ topk, float* __restrict__ out) {
    __shared__ unsigned hist[2048];
    __shared__ unsigned part[256];
    __shared__ float coll[1024];
    __shared__ unsigned ncoll;
    __shared__ int sTb;
    __shared__ unsigned sC1;
    __shared__ float wsum[4];
    int t = threadIdx.x, b = blockIdx.x;
    int k1 = topk[0] - 1;
    unsigned c = cnt[b]; if (c > CAP) c = CAP;
    float invw = 2048.f / cutoff[b];
    for (int i = t; i < 2048; i += 256) hist[i] = 0;
    if (t == 0) ncoll = 0;
    __syncthreads();
    const float* vals = buf + (long)b * CAP;
    for (unsigned i = t; i < c; i += 256) {
        float d = vals[i];
        int bin = (int)(d * invw);
        bin = bin < 0 ? 0 : (bin > 2047 ? 2047 : bin);
        atomicAdd(&hist[bin], 1u);
    }
    __syncthreads();
    unsigned p = 0;
    for (int j = 0; j < 8; j++) p += hist[t * 8 + j];
    part[t] = p;
    __syncthreads();
    if (t == 0) {
        unsigned tgt = (c < (unsigned)k1) ? c : (unsigned)k1;
        unsigned cum = 0; int Tb = 2048; unsigned C1 = 0;
        if (tgt > 0) {
            for (int i = 0; i < 256; i++) {
                if (cum + part[i] >= tgt) {
                    for (int j = 0; j < 8; j++) {
                        int bb = i * 8 + j;
                        if (cum + hist[bb] >= tgt) { Tb = bb; C1 = cum; break; }
                        cum += hist[bb];
                    }
                    break;
                }
                cum += part[i];
            }
        }
        sTb = Tb; sC1 = C1;
    }
    __syncthreads();
    int Tb = sTb; unsigned C1 = sC1;
    float ls = 0.f;
    for (unsigned i = t; i < c; i += 256) {
        float d = vals[i];
        int bin = (int)(d * invw);
        bin = bin < 0 ? 0 : (bin > 2047 ? 2047 : bin);
        if (bin < Tb) ls += d;
        else if (bin == Tb) {
            unsigned ix = atomicAdd(&ncoll, 1u);
            if (ix < 1024) coll[ix] = d;
        }
    }
    ls += __shfl_down(ls, 32, 64); ls += __shfl_down(ls, 16, 64);
    ls += __shfl_down(ls, 8, 64);  ls += __shfl_down(ls, 4, 64);
    ls += __shfl_down(ls, 2, 64);  ls += __shfl_down(ls, 1, 64);
    if ((t & 63) == 0) wsum[t >> 6] = ls;
    __syncthreads();
    if (t == 0) {
        float S = wsum[0] + wsum[1] + wsum[2] + wsum[3];
        unsigned tgt = (c < (unsigned)k1) ? c : (unsigned)k1;
        int r = (int)(tgt - C1);
        unsigned nc = ncoll; if (nc > 1024) nc = 1024;
        for (int i = 0; i < r && i < (int)nc; i++) {
            float mn = 3.4e38f; int mi = 0;
            for (unsigned j = 0; j < nc; j++) if (coll[j] < mn) { mn = coll[j]; mi = (int)j; }
            S += mn; coll[mi] = 3.4e38f;
        }
        float minl = dpos[b];
        minl = minl < 1e-12f ? 1e-12f : (minl > 1e12f ? 1e12f : minl);
        minl += (float)(MEMN - 1) * 1e-12f;  // clip() lifts the M-1 zeros to 1e-12
        float maxl = S / (float)k1;
        float loss = minl - maxl + 1.0f; if (loss < 0.f) loss = 0.f;
        atomicAdd(&out[0], loss * (1.f / 128.f));
        atomicAdd(&out[1], minl * (1.f / 128.f));
        atomicAdd(&out[2], maxl * (1.f / 128.f));
    }
}

__global__ void k_sentinel(float* out) {
    out[0] = -777.f; out[1] = -777.f; out[2] = -777.f;
}

extern "C" void kernel_launch(void* const* d_in, const int* in_sizes, int n_in,
                              void* d_out, int out_size, void* d_ws, size_t ws_size,
                              hipStream_t stream) {
    const float* x     = (const float*)d_in[0];
    const int* labels  = (const int*)d_in[1];
    const float* Mem   = (const float*)d_in[2];
    const int* topk    = (const int*)d_in[3];
    (void)in_sizes; (void)n_in; (void)out_size;

    char* ws = (char*)d_ws;
    const size_t OFF_SAMP = 0;                       // 128*8192*4 = 4 MiB (transposed)
    const size_t OFF_BUF  = 4194304;                 // 128*16384*4 = 8 MiB
    const size_t OFF_CNT  = OFF_BUF + 8388608;
    const size_t OFF_XSQ  = OFF_CNT + 512;
    const size_t OFF_DPOS = OFF_XSQ + 512;
    const size_t OFF_CUT  = OFF_DPOS + 512;
    const size_t NEEDED   = OFF_CUT + 512;
    if (ws_size < NEEDED) {
        k_sentinel<<<1, 1, 0, stream>>>((float*)d_out);
        return;
    }
    float*    samp   = (float*)(ws + OFF_SAMP);
    float*    buf    = (float*)(ws + OFF_BUF);
    unsigned* cnt    = (unsigned*)(ws + OFF_CNT);
    float*    xsq    = (float*)(ws + OFF_XSQ);
    float*    dpos   = (float*)(ws + OFF_DPOS);
    float*    cutoff = (float*)(ws + OFF_CUT);

    k1_sample<<<SAMP / TILE_ROWS + 1, 512, 0, stream>>>(x, Mem, xsq, cnt, dpos,
                                                        (float*)d_out, samp);
    k2_cutoff<<<128,    256, 0, stream>>>(samp, xsq, cutoff);
    k3_gemm  <<<K3GRID, 512, 0, stream>>>(x, Mem, labels, xsq, cutoff, cnt, buf, dpos);
    k4_select<<<128,    256, 0, stream>>>(buf, cnt, cutoff, dpos, topk, (float*)d_out);
}